// Round 3
// baseline (553.447 us; speedup 1.0000x reference)
//
#include <hip/hip_runtime.h>
#include <hip/hip_bf16.h>

#define N_NODES 2048
#define D_NODE 128
#define QK_DIM 64
#define N_HEADS 8
#define E_DIM 8
#define EXP_SHIFT 24.0f

typedef __hip_bfloat16 bf16;
typedef unsigned short u16;
typedef __attribute__((ext_vector_type(8))) short bf16x8v;
typedef __attribute__((ext_vector_type(4))) float f32x4v;

__device__ __forceinline__ float bf2f(bf16 x) { return __bfloat162float(x); }
__device__ __forceinline__ float u2f(u16 u) { return __uint_as_float(((unsigned)u) << 16); }
__device__ __forceinline__ u16 f2bf(float f) {
  unsigned u = __float_as_uint(f);
  unsigned r = u + 0x7FFFu + ((u >> 16) & 1u);
  return (u16)(r >> 16);
}

__device__ __forceinline__ void unpack2(unsigned u, float& a, float& b) {
  union { unsigned x; float f; } lo, hi;
  lo.x = u << 16; hi.x = u & 0xffff0000u;
  a = lo.f; b = hi.f;
}
__device__ __forceinline__ void unpack8(uint4 u, float* f) {
  unpack2(u.x, f[0], f[1]); unpack2(u.y, f[2], f[3]);
  unpack2(u.z, f[4], f[5]); unpack2(u.w, f[6], f[7]);
}

template <bool BF16>
__device__ __forceinline__ float ldv(const void* p, size_t i) {
  if constexpr (BF16) return bf2f(((const bf16*)p)[i]);
  else return ((const float*)p)[i];
}
template <bool BF16>
__device__ __forceinline__ void ld8v(const void* p, size_t i8, float* f) {
  if constexpr (BF16) {
    uint4 u = ((const uint4*)p)[i8];
    unpack8(u, f);
  } else {
    const float4* fp = (const float4*)p;
    float4 a = fp[2 * i8], b = fp[2 * i8 + 1];
    f[0] = a.x; f[1] = a.y; f[2] = a.z; f[3] = a.w;
    f[4] = b.x; f[5] = b.y; f[6] = b.z; f[7] = b.w;
  }
}
template <bool BF16>
__device__ __forceinline__ void stv(void* p, size_t i, float v) {
  if constexpr (BF16) ((bf16*)p)[i] = __float2bfloat16(v);
  else ((float*)p)[i] = v;
}
template <bool BF16>
__device__ __forceinline__ void st8v(void* p, size_t i8, const float* f) {
  if constexpr (BF16) {
    union { uint4 u; u16 b[8]; } ou;
#pragma unroll
    for (int e = 0; e < 8; e++) ou.b[e] = f2bf(f[e]);
    ((uint4*)p)[i8] = ou.u;
  } else {
    ((float4*)p)[2 * i8] = make_float4(f[0], f[1], f[2], f[3]);
    ((float4*)p)[2 * i8 + 1] = make_float4(f[4], f[5], f[6], f[7]);
  }
}

// MFMA fragment load: 8 consecutive bf16 elements at elem (16B-aligned).
template <bool BF16>
__device__ __forceinline__ bf16x8v ld_frag(const void* p, size_t elem) {
  if constexpr (BF16) {
    return *(const bf16x8v*)((const u16*)p + elem);
  } else {
    const float4* fp = (const float4*)p;
    float4 a = fp[elem / 4], b = fp[elem / 4 + 1];
    union { bf16x8v v; u16 s[8]; } o;
    o.s[0] = f2bf(a.x); o.s[1] = f2bf(a.y); o.s[2] = f2bf(a.z); o.s[3] = f2bf(a.w);
    o.s[4] = f2bf(b.x); o.s[5] = f2bf(b.y); o.s[6] = f2bf(b.z); o.s[7] = f2bf(b.w);
    return o.v;
  }
}

// K0: dtype detect via adj[0][0]==1.0 (self-loop). bf16 word0 low16==0x3F80.
__global__ void k_detect(const unsigned* __restrict__ adj_words, int* __restrict__ flag) {
  if (threadIdx.x == 0 && blockIdx.x == 0) {
    int b = 0;
    for (int i = 0; i < 64; i++)
      if ((adj_words[i] & 0xFFFFu) == 0x3F80u) b = 1;
    *flag = b;
  }
}

// K1: projections as MFMA GEMM. Block = 16 nodes x 64 features (4 waves x 16 feat).
// grid (N/16, 24): mat = y>>3, h = y&7 (one head per y-block).
// W rows are read PERMUTED (row = d*8+h) so each wave's 16 features share h and
// have consecutive d -> Q/K stores become contiguous 32B runs (was 2B scatter).
template <bool BF16>
__global__ __launch_bounds__(256) void k_proj(
    const int* __restrict__ flag,
    const void* __restrict__ nodes, const void* __restrict__ WQ,
    const void* __restrict__ WK, const void* __restrict__ WV,
    u16* __restrict__ qhi, u16* __restrict__ qlo,
    u16* __restrict__ khi, u16* __restrict__ klo, u16* __restrict__ vT) {
  if ((*flag != 0) != BF16) return;
  int t = threadIdx.x;
  int n0 = blockIdx.x * 16;
  int g = blockIdx.y;
  int mat = g >> 3;
  int h = g & 7;
  const void* W = (mat == 0) ? WQ : (mat == 1) ? WK : WV;
  int wv = t >> 6, lane = t & 63, m0 = lane & 15, quad = lane >> 4;
  int d = wv * 16 + m0;          // feature d within head h
  int wrow = d * 8 + h;          // original column index into the 512
  f32x4v acc = {0.f, 0.f, 0.f, 0.f};
#pragma unroll
  for (int kk = 0; kk < 4; kk++) {
    bf16x8v af = ld_frag<BF16>(nodes, (size_t)(n0 + m0) * D_NODE + kk * 32 + quad * 8);
    bf16x8v bfr = ld_frag<BF16>(W, (size_t)wrow * D_NODE + kk * 32 + quad * 8);
    acc = __builtin_amdgcn_mfma_f32_16x16x32_bf16(af, bfr, acc, 0, 0, 0);
  }
  if (mat == 2) {
    union { unsigned w[2]; u16 s[4]; } ob;
#pragma unroll
    for (int reg = 0; reg < 4; reg++) ob.s[reg] = f2bf(acc[reg]);
    int n = n0 + quad * 4;
    unsigned* dst = (unsigned*)(vT + ((size_t)(h * QK_DIM + d)) * N_NODES + n);
    dst[0] = ob.w[0]; dst[1] = ob.w[1];
  } else {
    u16* hiP = (mat == 0) ? qhi : khi;
    u16* loP = (mat == 0) ? qlo : klo;
    float scale = (mat == 0) ? 0.125f : 1.f;
#pragma unroll
    for (int reg = 0; reg < 4; reg++) {
      int n = n0 + quad * 4 + reg;
      float vq = acc[reg] * scale;
      u16 hi = f2bf(vq);
      u16 lo = f2bf(vq - u2f(hi));
      size_t o = ((size_t)(h * N_NODES + n) << 6) + d;   // d consecutive across m0
      hiP[o] = hi; loP[o] = lo;
    }
  }
}

// K2 (fused), R2: 32-col super-tiles. Per (col-split, 16-row strip):
// each thread owns TWO pairs (r,cc) and (r,cc+16). 4 barriers / 32 cols (was 7).
// smod computed IN-PLACE in wes[h][16][33] (padded, bank-conflict-free).
// launch_bounds(256,4): grid = S*128 = 1024 = exactly 4 blocks/CU.
template <bool BF16>
__global__ __launch_bounds__(256, 4) void k_fused(
    const int* __restrict__ flag, int S,
    const void* __restrict__ adj, const void* __restrict__ edges,
    const void* __restrict__ We, const void* __restrict__ Weo,
    const u16* __restrict__ qhi, const u16* __restrict__ qlo,
    const u16* __restrict__ khi, const u16* __restrict__ klo,
    const u16* __restrict__ vT,
    float* __restrict__ hout_p, float* __restrict__ psum_p,
    void* __restrict__ out_base) {
  if ((*flag != 0) != BF16) return;
  __shared__ float We_s[N_HEADS][E_DIM];
  __shared__ float Weo_s[E_DIM][N_HEADS];
  __shared__ float wes[N_HEADS][16][33];   // we*a, then smod in-place; +1 pad
  __shared__ u16 p_tile[N_HEADS][16][32];
  int t = threadIdx.x;
  if (t < 64) { We_s[t >> 3][t & 7] = ldv<BF16>(We, t); Weo_s[t >> 3][t & 7] = ldv<BF16>(Weo, t); }
  int split = blockIdx.x, rt = blockIdx.y;
  int row0 = rt * 16;
  int nst = (N_NODES / 32) / S;            // super-tiles of 32 cols
  int colbase = split * nst * 32;
  int r = t >> 4, cc = t & 15;
  int wv = t >> 6, lane = t & 63, m0 = lane & 15, quad = lane >> 4;
  float psum[N_HEADS];
#pragma unroll
  for (int h = 0; h < 8; h++) psum[h] = 0.f;
  f32x4v acc_pv[2][4];
#pragma unroll
  for (int hh = 0; hh < 2; hh++)
#pragma unroll
    for (int dc = 0; dc < 4; dc++) acc_pv[hh][dc] = (f32x4v){0.f, 0.f, 0.f, 0.f};

  void* edges_out = (char*)out_base + (size_t)N_NODES * D_NODE * (BF16 ? 2 : 4);

  int nrow = row0 + r;
  // prologue: preload super-tile 0's adj/edges (2 pairs per thread)
  float a_c0, a_c1;
  float e8_c[16];
  {
    size_t p0 = (size_t)nrow * N_NODES + colbase + cc;
    a_c0 = ldv<BF16>(adj, p0);
    a_c1 = ldv<BF16>(adj, p0 + 16);
    ld8v<BF16>(edges, p0, e8_c);
    ld8v<BF16>(edges, p0 + 16, e8_c + 8);
  }

  for (int ct = 0; ct < nst; ct++) {
    int col0 = colbase + ct * 32;
    size_t pair0 = (size_t)nrow * N_NODES + col0 + cc;
    // prefetch next super-tile (wrap on last: harmless, result unused)
    int ctn = (ct + 1 < nst) ? (ct + 1) : 0;
    size_t pn = (size_t)nrow * N_NODES + colbase + ctn * 32 + cc;
    float a_n0 = ldv<BF16>(adj, pn);
    float a_n1 = ldv<BF16>(adj, pn + 16);
    float e8_n[16];
    ld8v<BF16>(edges, pn, e8_n);
    ld8v<BF16>(edges, pn + 16, e8_n + 8);

    __syncthreads();  // A: prev phase2/3 readers of wes done; phase4 p_tile readers done
    // --- phase 1: we*a for both halves ---
#pragma unroll
    for (int h = 0; h < 8; h++) {
      float w0 = 0.f, w1 = 0.f;
#pragma unroll
      for (int e = 0; e < 8; e++) {
        w0 += e8_c[e] * We_s[h][e];
        w1 += e8_c[e + 8] * We_s[h][e];
      }
      wes[h][r][cc] = w0 * a_c0;
      wes[h][r][cc + 16] = w1 * a_c1;
    }
    __syncthreads();  // B: wes visible
    // --- phase 2: QK^T MFMA (2 heads x 2 col-tiles per wave), smod in-place ---
#pragma unroll
    for (int hh = 0; hh < 2; hh++) {
      int h = wv * 2 + hh;
      size_t qbase = ((size_t)(h * N_NODES + row0 + m0) << 6) + quad * 8;
      bf16x8v qh0 = *(const bf16x8v*)(qhi + qbase);
      bf16x8v ql0 = *(const bf16x8v*)(qlo + qbase);
      bf16x8v qh1 = *(const bf16x8v*)(qhi + qbase + 32);
      bf16x8v ql1 = *(const bf16x8v*)(qlo + qbase + 32);
#pragma unroll
      for (int ch = 0; ch < 2; ch++) {
        int c0 = col0 + ch * 16;
        size_t kbase = ((size_t)(h * N_NODES + c0 + m0) << 6) + quad * 8;
        bf16x8v kh0 = *(const bf16x8v*)(khi + kbase);
        bf16x8v kl0 = *(const bf16x8v*)(klo + kbase);
        bf16x8v kh1 = *(const bf16x8v*)(khi + kbase + 32);
        bf16x8v kl1 = *(const bf16x8v*)(klo + kbase + 32);
        f32x4v acc = {0.f, 0.f, 0.f, 0.f};
        acc = __builtin_amdgcn_mfma_f32_16x16x32_bf16(qh0, kh0, acc, 0, 0, 0);
        acc = __builtin_amdgcn_mfma_f32_16x16x32_bf16(qh0, kl0, acc, 0, 0, 0);
        acc = __builtin_amdgcn_mfma_f32_16x16x32_bf16(ql0, kh0, acc, 0, 0, 0);
        acc = __builtin_amdgcn_mfma_f32_16x16x32_bf16(qh1, kh1, acc, 0, 0, 0);
        acc = __builtin_amdgcn_mfma_f32_16x16x32_bf16(qh1, kl1, acc, 0, 0, 0);
        acc = __builtin_amdgcn_mfma_f32_16x16x32_bf16(ql1, kh1, acc, 0, 0, 0);
#pragma unroll
        for (int reg = 0; reg < 4; reg++) {
          int i = quad * 4 + reg;
          wes[h][i][ch * 16 + m0] *= acc[reg];   // smod = S * (we*a)
        }
      }
    }
    __syncthreads();  // C: smod visible
    // --- phase 3: edges_out + p = exp(smod - C), two pairs sequentially ---
#pragma unroll
    for (int half = 0; half < 2; half++) {
      float sm[8];
#pragma unroll
      for (int h = 0; h < 8; h++) sm[h] = wes[h][r][half * 16 + cc];
      float av = half ? a_c1 : a_c0;
      float ss = 0.f, eo[8];
#pragma unroll
      for (int e = 0; e < 8; e++) {
        float x = e8_c[half * 8 + e];
#pragma unroll
        for (int h = 0; h < 8; h++) x += sm[h] * Weo_s[e][h];
        eo[e] = x; ss += x * x;
      }
      float inv = 1.f / (sqrtf(ss) + 1e-8f);
#pragma unroll
      for (int e = 0; e < 8; e++) eo[e] *= inv;
      st8v<BF16>(edges_out, pair0 + half * 16, eo);
#pragma unroll
      for (int h = 0; h < 8; h++) {
        float p = (av != 0.f) ? __expf(sm[h] - EXP_SHIFT) : 0.f;
        psum[h] += p;
        p_tile[h][r][half * 16 + cc] = f2bf(p);
      }
    }
    __syncthreads();  // D: p_tile visible
    // --- phase 4: PV MFMA, K=32 ---
#pragma unroll
    for (int hh = 0; hh < 2; hh++) {
      int h = wv * 2 + hh;
      bf16x8v ap = *(const bf16x8v*)(&p_tile[h][0][0] + m0 * 32 + quad * 8);
#pragma unroll
      for (int dc = 0; dc < 4; dc++) {
        bf16x8v bp = *(const bf16x8v*)(vT + ((size_t)(h * QK_DIM + dc * 16 + m0)) * N_NODES + col0 + quad * 8);
        acc_pv[hh][dc] = __builtin_amdgcn_mfma_f32_16x16x32_bf16(ap, bp, acc_pv[hh][dc], 0, 0, 0);
      }
    }
    // rotate pipeline registers
    a_c0 = a_n0; a_c1 = a_n1;
#pragma unroll
    for (int e = 0; e < 16; e++) e8_c[e] = e8_n[e];
  }
  // --- epilogue: psum reduce over the 16 col-lanes; write partials ---
#pragma unroll
  for (int h = 0; h < 8; h++) {
    float x = psum[h];
    x += __shfl_xor(x, 1); x += __shfl_xor(x, 2);
    x += __shfl_xor(x, 4); x += __shfl_xor(x, 8);
    if ((t & 15) == 0)
      psum_p[((size_t)(row0 + r)) * (S * 8) + split * 8 + h] = x;
  }
#pragma unroll
  for (int hh = 0; hh < 2; hh++) {
    int h = wv * 2 + hh;
#pragma unroll
    for (int dc = 0; dc < 4; dc++) {
#pragma unroll
      for (int reg = 0; reg < 4; reg++) {
        int nn = row0 + quad * 4 + reg;
        hout_p[((size_t)nn * S + split) * 512 + h * 64 + dc * 16 + m0] = acc_pv[hh][dc][reg];
      }
    }
  }
}

// K3: one-time transpose Wo[128][512] -> WoT[512][128] fp32 (coalesced k_out reads)
template <bool BF16>
__global__ void k_wot(const int* __restrict__ flag, const void* __restrict__ Wo,
                      float* __restrict__ WoT) {
  if ((*flag != 0) != BF16) return;
  int idx = blockIdx.x * 256 + threadIdx.x;   // 65536 elems
  int o = idx >> 9, f = idx & 511;
  WoT[(size_t)f * D_NODE + o] = ldv<BF16>(Wo, (size_t)o * 512 + f);
}

// K4: merge partials + nodes_out = l2norm(nodes + h @ Wo^T + bo).
// Reads WoT coalesced (4B/lane contiguous); psum merge parallelized.
template <bool BF16>
__global__ __launch_bounds__(128) void k_out(
    const int* __restrict__ flag, int S,
    const void* __restrict__ nodes, const float* __restrict__ WoT,
    const void* __restrict__ bo,
    const float* __restrict__ hout_p, const float* __restrict__ psum_p,
    void* __restrict__ out_base) {
  if ((*flag != 0) != BF16) return;
  int n = blockIdx.x, t = threadIdx.x;
  __shared__ float hv[QK_DIM * N_HEADS];
  __shared__ float inv_s[N_HEADS];
  __shared__ float red[128];
  if (t < 64) red[t] = (t < S * 8) ? psum_p[(size_t)n * (S * 8) + t] : 0.f;
  __syncthreads();
  if (t < 8) {
    float tot = 0.f;
#pragma unroll
    for (int s = 0; s < 8; s++) tot += red[s * 8 + t];
    inv_s[t] = (tot > 0.f) ? 1.f / tot : 0.f;
  }
  __syncthreads();
  for (int i = t; i < QK_DIM * N_HEADS; i += 128) {
    int d = i >> 3, hh = i & 7;
    float acc = 0.f;
    for (int s = 0; s < S; s++)
      acc += hout_p[((size_t)n * S + s) * 512 + hh * 64 + d];
    hv[i] = acc * inv_s[hh];
  }
  __syncthreads();
  float val = ldv<BF16>(nodes, (size_t)n * D_NODE + t) + ldv<BF16>(bo, t);
#pragma unroll 8
  for (int j = 0; j < 512; j++) val += WoT[(size_t)j * D_NODE + t] * hv[j];
  red[t] = val * val;
  __syncthreads();
  for (int s = 64; s > 0; s >>= 1) {
    if (t < s) red[t] += red[t + s];
    __syncthreads();
  }
  float ss = red[0];
  stv<BF16>(out_base, (size_t)n * D_NODE + t, val / (sqrtf(ss) + 1e-8f));
}

extern "C" void kernel_launch(void* const* d_in, const int* in_sizes, int n_in,
                              void* d_out, int out_size, void* d_ws, size_t ws_size,
                              hipStream_t stream) {
  const void* nodes = d_in[0];
  const void* adj   = d_in[1];
  const void* edges = d_in[2];
  const void* WQ = d_in[3];
  const void* WK = d_in[4];
  const void* WV = d_in[5];
  const void* Wo = d_in[6];
  const void* bo = d_in[7];
  const void* We = d_in[8];
  const void* Weo = d_in[9];

  // ws: [flag 256B][qhi qlo khi klo vT : 5 x 2MB][WoT 256KB][hout_p S*4MB][psum_p S*64KB]
  char* w = (char*)d_ws;
  int* flag = (int*)w;
  size_t off = 256;
  const size_t PLANE = (size_t)N_HEADS * N_NODES * QK_DIM * 2;  // 2 MB
  u16* qhi = (u16*)(w + off);  off += PLANE;
  u16* qlo = (u16*)(w + off);  off += PLANE;
  u16* khi = (u16*)(w + off);  off += PLANE;
  u16* klo = (u16*)(w + off);  off += PLANE;
  u16* vT  = (u16*)(w + off);  off += PLANE;
  float* WoT = (float*)(w + off);  off += (size_t)512 * D_NODE * 4;

  int S = 8;
  while (S > 1 && off + (size_t)S * ((size_t)N_NODES * 512 * 4 + N_NODES * 8 * 4) > ws_size)
    S >>= 1;
  float* hout_p = (float*)(w + off);
  off += (size_t)S * N_NODES * 512 * 4;
  float* psum_p = (float*)(w + off);

  k_detect<<<1, 64, 0, stream>>>((const unsigned*)adj, flag);

  dim3 g1(N_NODES / 16, 24);
  k_proj<false><<<g1, 256, 0, stream>>>(flag, nodes, WQ, WK, WV, qhi, qlo, khi, klo, vT);
  k_proj<true ><<<g1, 256, 0, stream>>>(flag, nodes, WQ, WK, WV, qhi, qlo, khi, klo, vT);

  k_wot<false><<<256, 256, 0, stream>>>(flag, Wo, WoT);
  k_wot<true ><<<256, 256, 0, stream>>>(flag, Wo, WoT);

  dim3 g2(S, N_NODES / 16);
  k_fused<false><<<g2, 256, 0, stream>>>(flag, S, adj, edges, We, Weo,
                                         qhi, qlo, khi, klo, vT, hout_p, psum_p, d_out);
  k_fused<true ><<<g2, 256, 0, stream>>>(flag, S, adj, edges, We, Weo,
                                         qhi, qlo, khi, klo, vT, hout_p, psum_p, d_out);

  k_out<false><<<N_NODES, 128, 0, stream>>>(flag, S, nodes, WoT, bo, hout_p, psum_p, d_out);
  k_out<true ><<<N_NODES, 128, 0, stream>>>(flag, S, nodes, WoT, bo, hout_p, psum_p, d_out);
}

// Round 4
// 410.876 us; speedup vs baseline: 1.3470x; 1.3470x over previous
//
#include <hip/hip_runtime.h>
#include <hip/hip_bf16.h>

#define N_NODES 2048
#define D_NODE 128
#define QK_DIM 64
#define N_HEADS 8
#define E_DIM 8
#define EXP_SHIFT 24.0f

typedef __hip_bfloat16 bf16;
typedef unsigned short u16;
typedef __attribute__((ext_vector_type(8))) short bf16x8v;
typedef __attribute__((ext_vector_type(4))) float f32x4v;

__device__ __forceinline__ float bf2f(bf16 x) { return __bfloat162float(x); }
__device__ __forceinline__ float u2f(u16 u) { return __uint_as_float(((unsigned)u) << 16); }
__device__ __forceinline__ u16 f2bf(float f) {
  unsigned u = __float_as_uint(f);
  unsigned r = u + 0x7FFFu + ((u >> 16) & 1u);
  return (u16)(r >> 16);
}

__device__ __forceinline__ void unpack2(unsigned u, float& a, float& b) {
  union { unsigned x; float f; } lo, hi;
  lo.x = u << 16; hi.x = u & 0xffff0000u;
  a = lo.f; b = hi.f;
}
__device__ __forceinline__ void unpack8(uint4 u, float* f) {
  unpack2(u.x, f[0], f[1]); unpack2(u.y, f[2], f[3]);
  unpack2(u.z, f[4], f[5]); unpack2(u.w, f[6], f[7]);
}

template <bool BF16>
__device__ __forceinline__ float ldv(const void* p, size_t i) {
  if constexpr (BF16) return bf2f(((const bf16*)p)[i]);
  else return ((const float*)p)[i];
}
template <bool BF16>
__device__ __forceinline__ void ld8v(const void* p, size_t i8, float* f) {
  if constexpr (BF16) {
    uint4 u = ((const uint4*)p)[i8];
    unpack8(u, f);
  } else {
    const float4* fp = (const float4*)p;
    float4 a = fp[2 * i8], b = fp[2 * i8 + 1];
    f[0] = a.x; f[1] = a.y; f[2] = a.z; f[3] = a.w;
    f[4] = b.x; f[5] = b.y; f[6] = b.z; f[7] = b.w;
  }
}
template <bool BF16>
__device__ __forceinline__ void stv(void* p, size_t i, float v) {
  if constexpr (BF16) ((bf16*)p)[i] = __float2bfloat16(v);
  else ((float*)p)[i] = v;
}
template <bool BF16>
__device__ __forceinline__ void st8v(void* p, size_t i8, const float* f) {
  if constexpr (BF16) {
    union { uint4 u; u16 b[8]; } ou;
#pragma unroll
    for (int e = 0; e < 8; e++) ou.b[e] = f2bf(f[e]);
    ((uint4*)p)[i8] = ou.u;
  } else {
    ((float4*)p)[2 * i8] = make_float4(f[0], f[1], f[2], f[3]);
    ((float4*)p)[2 * i8 + 1] = make_float4(f[4], f[5], f[6], f[7]);
  }
}

// MFMA fragment load: 8 consecutive bf16 elements at elem (16B-aligned).
template <bool BF16>
__device__ __forceinline__ bf16x8v ld_frag(const void* p, size_t elem) {
  if constexpr (BF16) {
    return *(const bf16x8v*)((const u16*)p + elem);
  } else {
    const float4* fp = (const float4*)p;
    float4 a = fp[elem / 4], b = fp[elem / 4 + 1];
    union { bf16x8v v; u16 s[8]; } o;
    o.s[0] = f2bf(a.x); o.s[1] = f2bf(a.y); o.s[2] = f2bf(a.z); o.s[3] = f2bf(a.w);
    o.s[4] = f2bf(b.x); o.s[5] = f2bf(b.y); o.s[6] = f2bf(b.z); o.s[7] = f2bf(b.w);
    return o.v;
  }
}

// K0: dtype detect via adj[0][0]==1.0 (self-loop). bf16 word0 low16==0x3F80.
__global__ void k_detect(const unsigned* __restrict__ adj_words, int* __restrict__ flag) {
  if (threadIdx.x == 0 && blockIdx.x == 0) {
    int b = 0;
    for (int i = 0; i < 64; i++)
      if ((adj_words[i] & 0xFFFFu) == 0x3F80u) b = 1;
    *flag = b;
  }
}

// K1: projections as MFMA GEMM + (y==24) Wo transpose slice.
// Block = 16 nodes x 64 features (4 waves x 16 feat).
// grid (N/16, 25): y<24: mat = y>>3, h = y&7 (one head per y-block).
// W rows are read PERMUTED (row = d*8+h) so each wave's 16 features share h and
// have consecutive d -> Q/K stores become contiguous 32B runs.
// y==24: transpose Wo[128][512] -> WoT[512][128] fp32 (2 elems/thread).
template <bool BF16>
__global__ __launch_bounds__(256) void k_proj(
    const int* __restrict__ flag,
    const void* __restrict__ nodes, const void* __restrict__ WQ,
    const void* __restrict__ WK, const void* __restrict__ WV,
    const void* __restrict__ Wo, float* __restrict__ WoT,
    u16* __restrict__ qhi, u16* __restrict__ qlo,
    u16* __restrict__ khi, u16* __restrict__ klo, u16* __restrict__ vT) {
  if ((*flag != 0) != BF16) return;
  int t = threadIdx.x;
  int g = blockIdx.y;
  if (g == 24) {  // WoT slice: block x covers o=x, f=2t..2t+1
    int idx = ((int)blockIdx.x * 256 + t) * 2;
    int o = idx >> 9, f = idx & 511;
    WoT[(size_t)f * D_NODE + o] = ldv<BF16>(Wo, (size_t)o * 512 + f);
    WoT[(size_t)(f + 1) * D_NODE + o] = ldv<BF16>(Wo, (size_t)o * 512 + f + 1);
    return;
  }
  int n0 = blockIdx.x * 16;
  int mat = g >> 3;
  int h = g & 7;
  const void* W = (mat == 0) ? WQ : (mat == 1) ? WK : WV;
  int wv = t >> 6, lane = t & 63, m0 = lane & 15, quad = lane >> 4;
  int d = wv * 16 + m0;          // feature d within head h
  int wrow = d * 8 + h;          // original column index into the 512
  f32x4v acc = {0.f, 0.f, 0.f, 0.f};
#pragma unroll
  for (int kk = 0; kk < 4; kk++) {
    bf16x8v af = ld_frag<BF16>(nodes, (size_t)(n0 + m0) * D_NODE + kk * 32 + quad * 8);
    bf16x8v bfr = ld_frag<BF16>(W, (size_t)wrow * D_NODE + kk * 32 + quad * 8);
    acc = __builtin_amdgcn_mfma_f32_16x16x32_bf16(af, bfr, acc, 0, 0, 0);
  }
  if (mat == 2) {
    union { unsigned w[2]; u16 s[4]; } ob;
#pragma unroll
    for (int reg = 0; reg < 4; reg++) ob.s[reg] = f2bf(acc[reg]);
    int n = n0 + quad * 4;
    unsigned* dst = (unsigned*)(vT + ((size_t)(h * QK_DIM + d)) * N_NODES + n);
    dst[0] = ob.w[0]; dst[1] = ob.w[1];
  } else {
    u16* hiP = (mat == 0) ? qhi : khi;
    u16* loP = (mat == 0) ? qlo : klo;
    float scale = (mat == 0) ? 0.125f : 1.f;
#pragma unroll
    for (int reg = 0; reg < 4; reg++) {
      int n = n0 + quad * 4 + reg;
      float vq = acc[reg] * scale;
      u16 hi = f2bf(vq);
      u16 lo = f2bf(vq - u2f(hi));
      size_t o = ((size_t)(h * N_NODES + n) << 6) + d;   // d consecutive across m0
      hiP[o] = hi; loP[o] = lo;
    }
  }
}

// K2 (fused), R3: 32-col super-tiles, 4 barriers / 32 cols, padded wes.
// launch_bounds(256, 2): VGPR cap 128 (empirical: cap = 256/min_waves).
// R2's (256,4) capped at 64 VGPR -> ~520 MB of scratch spill traffic (FETCH
// 102->390, WRITE 164->384 MB). Body needs ~126 live VGPRs; 128 cap fits and
// <=128 VGPR still yields 4 waves/SIMD residency for the 1024-block grid.
template <bool BF16>
__global__ __launch_bounds__(256, 2) void k_fused(
    const int* __restrict__ flag, int S,
    const void* __restrict__ adj, const void* __restrict__ edges,
    const void* __restrict__ We, const void* __restrict__ Weo,
    const u16* __restrict__ qhi, const u16* __restrict__ qlo,
    const u16* __restrict__ khi, const u16* __restrict__ klo,
    const u16* __restrict__ vT,
    float* __restrict__ hout_p, float* __restrict__ psum_p,
    void* __restrict__ out_base) {
  if ((*flag != 0) != BF16) return;
  __shared__ float We_s[N_HEADS][E_DIM];
  __shared__ float Weo_s[E_DIM][N_HEADS];
  __shared__ float wes[N_HEADS][16][33];   // we*a, then smod in-place; +1 pad
  __shared__ u16 p_tile[N_HEADS][16][32];
  int t = threadIdx.x;
  if (t < 64) { We_s[t >> 3][t & 7] = ldv<BF16>(We, t); Weo_s[t >> 3][t & 7] = ldv<BF16>(Weo, t); }
  int split = blockIdx.x, rt = blockIdx.y;
  int row0 = rt * 16;
  int nst = (N_NODES / 32) / S;            // super-tiles of 32 cols
  int colbase = split * nst * 32;
  int r = t >> 4, cc = t & 15;
  int wv = t >> 6, lane = t & 63, m0 = lane & 15, quad = lane >> 4;
  float psum[N_HEADS];
#pragma unroll
  for (int h = 0; h < 8; h++) psum[h] = 0.f;
  f32x4v acc_pv[2][4];
#pragma unroll
  for (int hh = 0; hh < 2; hh++)
#pragma unroll
    for (int dc = 0; dc < 4; dc++) acc_pv[hh][dc] = (f32x4v){0.f, 0.f, 0.f, 0.f};

  void* edges_out = (char*)out_base + (size_t)N_NODES * D_NODE * (BF16 ? 2 : 4);

  int nrow = row0 + r;
  // prologue: preload super-tile 0's adj/edges (2 pairs per thread)
  float a_c0, a_c1;
  float e8_c[16];
  {
    size_t p0 = (size_t)nrow * N_NODES + colbase + cc;
    a_c0 = ldv<BF16>(adj, p0);
    a_c1 = ldv<BF16>(adj, p0 + 16);
    ld8v<BF16>(edges, p0, e8_c);
    ld8v<BF16>(edges, p0 + 16, e8_c + 8);
  }

  for (int ct = 0; ct < nst; ct++) {
    int col0 = colbase + ct * 32;
    size_t pair0 = (size_t)nrow * N_NODES + col0 + cc;
    // prefetch next super-tile (wrap on last: harmless, result unused)
    int ctn = (ct + 1 < nst) ? (ct + 1) : 0;
    size_t pn = (size_t)nrow * N_NODES + colbase + ctn * 32 + cc;
    float a_n0 = ldv<BF16>(adj, pn);
    float a_n1 = ldv<BF16>(adj, pn + 16);
    float e8_n[16];
    ld8v<BF16>(edges, pn, e8_n);
    ld8v<BF16>(edges, pn + 16, e8_n + 8);

    __syncthreads();  // A: prev phase2/3 readers of wes done; phase4 p_tile readers done
    // --- phase 1: we*a for both halves ---
#pragma unroll
    for (int h = 0; h < 8; h++) {
      float w0 = 0.f, w1 = 0.f;
#pragma unroll
      for (int e = 0; e < 8; e++) {
        w0 += e8_c[e] * We_s[h][e];
        w1 += e8_c[e + 8] * We_s[h][e];
      }
      wes[h][r][cc] = w0 * a_c0;
      wes[h][r][cc + 16] = w1 * a_c1;
    }
    __syncthreads();  // B: wes visible
    // --- phase 2: QK^T MFMA (2 heads x 2 col-tiles per wave), smod in-place ---
#pragma unroll
    for (int hh = 0; hh < 2; hh++) {
      int h = wv * 2 + hh;
      size_t qbase = ((size_t)(h * N_NODES + row0 + m0) << 6) + quad * 8;
      bf16x8v qh0 = *(const bf16x8v*)(qhi + qbase);
      bf16x8v ql0 = *(const bf16x8v*)(qlo + qbase);
      bf16x8v qh1 = *(const bf16x8v*)(qhi + qbase + 32);
      bf16x8v ql1 = *(const bf16x8v*)(qlo + qbase + 32);
#pragma unroll
      for (int ch = 0; ch < 2; ch++) {
        int c0 = col0 + ch * 16;
        size_t kbase = ((size_t)(h * N_NODES + c0 + m0) << 6) + quad * 8;
        bf16x8v kh0 = *(const bf16x8v*)(khi + kbase);
        bf16x8v kl0 = *(const bf16x8v*)(klo + kbase);
        bf16x8v kh1 = *(const bf16x8v*)(khi + kbase + 32);
        bf16x8v kl1 = *(const bf16x8v*)(klo + kbase + 32);
        f32x4v acc = {0.f, 0.f, 0.f, 0.f};
        acc = __builtin_amdgcn_mfma_f32_16x16x32_bf16(qh0, kh0, acc, 0, 0, 0);
        acc = __builtin_amdgcn_mfma_f32_16x16x32_bf16(qh0, kl0, acc, 0, 0, 0);
        acc = __builtin_amdgcn_mfma_f32_16x16x32_bf16(ql0, kh0, acc, 0, 0, 0);
        acc = __builtin_amdgcn_mfma_f32_16x16x32_bf16(qh1, kh1, acc, 0, 0, 0);
        acc = __builtin_amdgcn_mfma_f32_16x16x32_bf16(qh1, kl1, acc, 0, 0, 0);
        acc = __builtin_amdgcn_mfma_f32_16x16x32_bf16(ql1, kh1, acc, 0, 0, 0);
#pragma unroll
        for (int reg = 0; reg < 4; reg++) {
          int i = quad * 4 + reg;
          wes[h][i][ch * 16 + m0] *= acc[reg];   // smod = S * (we*a)
        }
      }
    }
    __syncthreads();  // C: smod visible
    // --- phase 3: edges_out + p = exp(smod - C), two pairs sequentially ---
#pragma unroll
    for (int half = 0; half < 2; half++) {
      float sm[8];
#pragma unroll
      for (int h = 0; h < 8; h++) sm[h] = wes[h][r][half * 16 + cc];
      float av = half ? a_c1 : a_c0;
      float ss = 0.f, eo[8];
#pragma unroll
      for (int e = 0; e < 8; e++) {
        float x = e8_c[half * 8 + e];
#pragma unroll
        for (int h = 0; h < 8; h++) x += sm[h] * Weo_s[e][h];
        eo[e] = x; ss += x * x;
      }
      float inv = 1.f / (sqrtf(ss) + 1e-8f);
#pragma unroll
      for (int e = 0; e < 8; e++) eo[e] *= inv;
      st8v<BF16>(edges_out, pair0 + half * 16, eo);
#pragma unroll
      for (int h = 0; h < 8; h++) {
        float p = (av != 0.f) ? __expf(sm[h] - EXP_SHIFT) : 0.f;
        psum[h] += p;
        p_tile[h][r][half * 16 + cc] = f2bf(p);
      }
    }
    __syncthreads();  // D: p_tile visible
    // --- phase 4: PV MFMA, K=32 ---
#pragma unroll
    for (int hh = 0; hh < 2; hh++) {
      int h = wv * 2 + hh;
      bf16x8v ap = *(const bf16x8v*)(&p_tile[h][0][0] + m0 * 32 + quad * 8);
#pragma unroll
      for (int dc = 0; dc < 4; dc++) {
        bf16x8v bp = *(const bf16x8v*)(vT + ((size_t)(h * QK_DIM + dc * 16 + m0)) * N_NODES + col0 + quad * 8);
        acc_pv[hh][dc] = __builtin_amdgcn_mfma_f32_16x16x32_bf16(ap, bp, acc_pv[hh][dc], 0, 0, 0);
      }
    }
    // rotate pipeline registers
    a_c0 = a_n0; a_c1 = a_n1;
#pragma unroll
    for (int e = 0; e < 16; e++) e8_c[e] = e8_n[e];
  }
  // --- epilogue: psum reduce over the 16 col-lanes; write partials ---
#pragma unroll
  for (int h = 0; h < 8; h++) {
    float x = psum[h];
    x += __shfl_xor(x, 1); x += __shfl_xor(x, 2);
    x += __shfl_xor(x, 4); x += __shfl_xor(x, 8);
    if ((t & 15) == 0)
      psum_p[((size_t)(row0 + r)) * (S * 8) + split * 8 + h] = x;
  }
#pragma unroll
  for (int hh = 0; hh < 2; hh++) {
    int h = wv * 2 + hh;
#pragma unroll
    for (int dc = 0; dc < 4; dc++) {
#pragma unroll
      for (int reg = 0; reg < 4; reg++) {
        int nn = row0 + quad * 4 + reg;
        hout_p[((size_t)nn * S + split) * 512 + h * 64 + dc * 16 + m0] = acc_pv[hh][dc][reg];
      }
    }
  }
}

// K4: merge partials + nodes_out = l2norm(nodes + h @ Wo^T + bo).
// Reads WoT coalesced (4B/lane contiguous); psum merge parallelized.
template <bool BF16>
__global__ __launch_bounds__(128) void k_out(
    const int* __restrict__ flag, int S,
    const void* __restrict__ nodes, const float* __restrict__ WoT,
    const void* __restrict__ bo,
    const float* __restrict__ hout_p, const float* __restrict__ psum_p,
    void* __restrict__ out_base) {
  if ((*flag != 0) != BF16) return;
  int n = blockIdx.x, t = threadIdx.x;
  __shared__ float hv[QK_DIM * N_HEADS];
  __shared__ float inv_s[N_HEADS];
  __shared__ float red[128];
  if (t < 64) red[t] = (t < S * 8) ? psum_p[(size_t)n * (S * 8) + t] : 0.f;
  __syncthreads();
  if (t < 8) {
    float tot = 0.f;
#pragma unroll
    for (int s = 0; s < 8; s++) tot += red[s * 8 + t];
    inv_s[t] = (tot > 0.f) ? 1.f / tot : 0.f;
  }
  __syncthreads();
  for (int i = t; i < QK_DIM * N_HEADS; i += 128) {
    int d = i >> 3, hh = i & 7;
    float acc = 0.f;
    for (int s = 0; s < S; s++)
      acc += hout_p[((size_t)n * S + s) * 512 + hh * 64 + d];
    hv[i] = acc * inv_s[hh];
  }
  __syncthreads();
  float val = ldv<BF16>(nodes, (size_t)n * D_NODE + t) + ldv<BF16>(bo, t);
#pragma unroll 8
  for (int j = 0; j < 512; j++) val += WoT[(size_t)j * D_NODE + t] * hv[j];
  red[t] = val * val;
  __syncthreads();
  for (int s = 64; s > 0; s >>= 1) {
    if (t < s) red[t] += red[t + s];
    __syncthreads();
  }
  float ss = red[0];
  stv<BF16>(out_base, (size_t)n * D_NODE + t, val / (sqrtf(ss) + 1e-8f));
}

extern "C" void kernel_launch(void* const* d_in, const int* in_sizes, int n_in,
                              void* d_out, int out_size, void* d_ws, size_t ws_size,
                              hipStream_t stream) {
  const void* nodes = d_in[0];
  const void* adj   = d_in[1];
  const void* edges = d_in[2];
  const void* WQ = d_in[3];
  const void* WK = d_in[4];
  const void* WV = d_in[5];
  const void* Wo = d_in[6];
  const void* bo = d_in[7];
  const void* We = d_in[8];
  const void* Weo = d_in[9];

  // ws: [flag 256B][qhi qlo khi klo vT : 5 x 2MB][WoT 256KB][hout_p S*4MB][psum_p S*64KB]
  char* w = (char*)d_ws;
  int* flag = (int*)w;
  size_t off = 256;
  const size_t PLANE = (size_t)N_HEADS * N_NODES * QK_DIM * 2;  // 2 MB
  u16* qhi = (u16*)(w + off);  off += PLANE;
  u16* qlo = (u16*)(w + off);  off += PLANE;
  u16* khi = (u16*)(w + off);  off += PLANE;
  u16* klo = (u16*)(w + off);  off += PLANE;
  u16* vT  = (u16*)(w + off);  off += PLANE;
  float* WoT = (float*)(w + off);  off += (size_t)512 * D_NODE * 4;

  int S = 8;
  while (S > 1 && off + (size_t)S * ((size_t)N_NODES * 512 * 4 + N_NODES * 8 * 4) > ws_size)
    S >>= 1;
  float* hout_p = (float*)(w + off);
  off += (size_t)S * N_NODES * 512 * 4;
  float* psum_p = (float*)(w + off);

  k_detect<<<1, 64, 0, stream>>>((const unsigned*)adj, flag);

  dim3 g1(N_NODES / 16, 25);
  k_proj<false><<<g1, 256, 0, stream>>>(flag, nodes, WQ, WK, WV, Wo, WoT, qhi, qlo, khi, klo, vT);
  k_proj<true ><<<g1, 256, 0, stream>>>(flag, nodes, WQ, WK, WV, Wo, WoT, qhi, qlo, khi, klo, vT);

  dim3 g2(S, N_NODES / 16);
  k_fused<false><<<g2, 256, 0, stream>>>(flag, S, adj, edges, We, Weo,
                                         qhi, qlo, khi, klo, vT, hout_p, psum_p, d_out);
  k_fused<true ><<<g2, 256, 0, stream>>>(flag, S, adj, edges, We, Weo,
                                         qhi, qlo, khi, klo, vT, hout_p, psum_p, d_out);

  k_out<false><<<N_NODES, 128, 0, stream>>>(flag, S, nodes, WoT, bo, hout_p, psum_p, d_out);
  k_out<true ><<<N_NODES, 128, 0, stream>>>(flag, S, nodes, WoT, bo, hout_p, psum_p, d_out);
}